// Round 2
// baseline (791.671 us; speedup 1.0000x reference)
//
#include <hip/hip_runtime.h>
#include <hip/hip_bf16.h>
#include <math.h>

typedef __bf16 bf16_t;
typedef __bf16 bf16x8 __attribute__((ext_vector_type(8)));
typedef __bf16 bf16x4 __attribute__((ext_vector_type(4)));
typedef float  f32x4  __attribute__((ext_vector_type(4)));

#define B_   8
#define L_   1024
#define D_   512
#define H_   8
#define HD_  4096   // H*D
#define BL_  8192   // B*L

__device__ __forceinline__ void gload_lds16(const bf16_t* g, bf16_t* l) {
  __builtin_amdgcn_global_load_lds(
      (const __attribute__((address_space(1))) unsigned int*)g,
      (__attribute__((address_space(3))) unsigned int*)l,
      16, 0, 0);
}

// ---------------- fp32 -> bf16 convert (vectorized) ----------------
__global__ void f2b(const float4* __restrict__ s, bf16x4* __restrict__ d, int n4) {
  int i = blockIdx.x * blockDim.x + threadIdx.x;
  if (i >= n4) return;
  float4 v = s[i];
  bf16x4 o;
  o[0] = (bf16_t)v.x; o[1] = (bf16_t)v.y; o[2] = (bf16_t)v.z; o[3] = (bf16_t)v.w;
  d[i] = o;
}

// ---------------- transpose + convert fp32(R,C) -> bf16(C,R) ----------------
__global__ void tconv(const float* __restrict__ s, bf16_t* __restrict__ d, int R, int C) {
  __shared__ float t[32][33];
  int c0 = blockIdx.x * 32, r0 = blockIdx.y * 32;
  int tx = threadIdx.x, ty = threadIdx.y;
  #pragma unroll
  for (int i = 0; i < 32; i += 8)
    t[ty + i][tx] = s[(long)(r0 + ty + i) * C + c0 + tx];
  __syncthreads();
  #pragma unroll
  for (int i = 0; i < 32; i += 8)
    d[(long)(c0 + ty + i) * R + r0 + tx] = (bf16_t)t[tx][ty + i];
}

// ------- per-(b,h) transpose bf16: vh_flat(8192,4096) -> vhT[bz](512,1024) -------
__global__ void tbf(const bf16_t* __restrict__ s, bf16_t* __restrict__ d) {
  __shared__ bf16_t t[32][33];
  int bz = blockIdx.z; int b = bz >> 3, h = bz & 7;
  const bf16_t* S = s + (long)b * L_ * HD_ + (long)h * D_;
  bf16_t* Dp = d + (long)bz * D_ * L_;
  int l0 = blockIdx.y * 32, d0 = blockIdx.x * 32;
  int tx = threadIdx.x, ty = threadIdx.y;
  #pragma unroll
  for (int i = 0; i < 32; i += 8)
    t[ty + i][tx] = S[(long)(l0 + ty + i) * HD_ + d0 + tx];
  __syncthreads();
  #pragma unroll
  for (int i = 0; i < 32; i += 8)
    Dp[(long)(d0 + ty + i) * L_ + l0 + tx] = t[tx][ty + i];
}

// ---------------- bf16 GEMM, A(M,K) x Bt(N,K)^T, 128x128 tile, BK=64 ----------------
// EPI 0: bf16 store; EPI 1: f32 store; EPI 2: f32 store + residual add
template<int EPI>
__launch_bounds__(256, 2)
__global__ void gemm_bt(const bf16_t* __restrict__ A, long sAb, long sAh, int lda,
                        const bf16_t* __restrict__ Bt, long sBb, long sBh, int ldb,
                        void* __restrict__ Cv, long sCb, long sCh, int ldc,
                        int K, float scale, const float* __restrict__ res)
{
  __shared__ bf16_t sA[128 * 64];
  __shared__ bf16_t sB[128 * 64];
  const int bz = blockIdx.z, b = bz >> 3, h = bz & 7;
  A  += (long)b * sAb + (long)h * sAh;
  Bt += (long)b * sBb + (long)h * sBh;
  const int m0 = blockIdx.y * 128, n0 = blockIdx.x * 128;
  const int tid = threadIdx.x, lane = tid & 63, wid = tid >> 6;
  const int waveM = wid >> 1, waveN = wid & 1;
  f32x4 acc[4][4] = {};
  const int srow = wid * 8 + (lane >> 3);
  const int skin = (lane & 7) * 8;
  const bf16_t* Ag = A + (long)(m0 + srow) * lda + skin;
  const bf16_t* Bg = Bt + (long)(n0 + srow) * ldb + skin;
  for (int k0 = 0; k0 < K; k0 += 64) {
    #pragma unroll
    for (int j = 0; j < 4; ++j) {
      gload_lds16(Ag + (long)(j * 32) * lda + k0, sA + (j * 4 + wid) * 512);
      gload_lds16(Bg + (long)(j * 32) * ldb + k0, sB + (j * 4 + wid) * 512);
    }
    __syncthreads();
    #pragma unroll
    for (int kk = 0; kk < 2; ++kk) {
      bf16x8 af[4], bfr[4];
      #pragma unroll
      for (int i = 0; i < 4; ++i) {
        af[i]  = *(const bf16x8*)(sA + (waveM * 64 + i * 16 + (lane & 15)) * 64 + kk * 32 + ((lane >> 4) * 8));
        bfr[i] = *(const bf16x8*)(sB + (waveN * 64 + i * 16 + (lane & 15)) * 64 + kk * 32 + ((lane >> 4) * 8));
      }
      #pragma unroll
      for (int i = 0; i < 4; ++i)
        #pragma unroll
        for (int j = 0; j < 4; ++j)
          acc[i][j] = __builtin_amdgcn_mfma_f32_16x16x32_bf16(af[i], bfr[j], acc[i][j], 0, 0, 0);
    }
    __syncthreads();
  }
  const long coff = (long)b * sCb + (long)h * sCh;
  #pragma unroll
  for (int i = 0; i < 4; ++i) {
    const int rbase = m0 + waveM * 64 + i * 16 + ((lane >> 4) << 2);
    #pragma unroll
    for (int j = 0; j < 4; ++j) {
      const int c = n0 + waveN * 64 + j * 16 + (lane & 15);
      #pragma unroll
      for (int r = 0; r < 4; ++r) {
        float v = acc[i][j][r] * scale;
        long idx = coff + (long)(rbase + r) * ldc + c;
        if (EPI == 0)      ((bf16_t*)Cv)[idx] = (bf16_t)v;
        else if (EPI == 1) ((float*)Cv)[idx] = v;
        else               ((float*)Cv)[idx] = v + res[(long)(rbase + r) * ldc + c];
      }
    }
  }
}

// ------------- fused softmax + PV: one block = 32 q-rows of one (b,h) -------------
// reads raw f32 scores, writes normalized f32 attn in place, bf16 P -> LDS
// (XOR-swizzled), then ctx = P @ vhT^T with B-fragments direct from global (L2).
#define QT_ 32
__launch_bounds__(256, 2)
__global__ void smpv(float* __restrict__ attn,          // (64,1024,1024) f32 in-place
                     const bf16_t* __restrict__ vhT,    // (64,512,1024) bf16
                     bf16_t* __restrict__ ctx)          // (8192,4096) bf16
{
  __shared__ __align__(16) bf16_t p[QT_ * 1024];        // 64 KiB
  char* pb = (char*)p;
  const int qt = blockIdx.x, bh = blockIdx.y;
  const int b = bh >> 3, h = bh & 7;
  const int tid = threadIdx.x, lane = tid & 63, wid = tid >> 6;
  float* A = attn + (long)bh * L_ * L_ + (long)qt * QT_ * L_;

  // ---- phase 1: softmax (wave w -> rows w*8 .. w*8+7) ----
  #pragma unroll
  for (int rr = 0; rr < 8; ++rr) {
    const int row = wid * 8 + rr;
    float* pr = A + (long)row * L_;
    float4 v[4];
    float m = -1e30f;
    #pragma unroll
    for (int j = 0; j < 4; ++j) {
      v[j] = ((const float4*)pr)[j * 64 + lane];
      m = fmaxf(fmaxf(fmaxf(v[j].x, v[j].y), fmaxf(v[j].z, v[j].w)), m);
    }
    #pragma unroll
    for (int o = 32; o; o >>= 1) m = fmaxf(m, __shfl_xor(m, o));
    float s = 0.f;
    #pragma unroll
    for (int j = 0; j < 4; ++j) {
      v[j].x = expf(v[j].x - m); v[j].y = expf(v[j].y - m);
      v[j].z = expf(v[j].z - m); v[j].w = expf(v[j].w - m);
      s += v[j].x + v[j].y + v[j].z + v[j].w;
    }
    #pragma unroll
    for (int o = 32; o; o >>= 1) s += __shfl_xor(s, o);
    const float inv = 1.f / s;
    const int swz = (row & 7) << 4;
    #pragma unroll
    for (int j = 0; j < 4; ++j) {
      v[j].x *= inv; v[j].y *= inv; v[j].z *= inv; v[j].w *= inv;
      ((float4*)pr)[j * 64 + lane] = v[j];
      bf16x4 o4;
      o4[0] = (bf16_t)v[j].x; o4[1] = (bf16_t)v[j].y;
      o4[2] = (bf16_t)v[j].z; o4[3] = (bf16_t)v[j].w;
      *(bf16x4*)(pb + ((row * 2048 + (j * 256 + lane * 4) * 2) ^ swz)) = o4;
    }
  }
  __syncthreads();

  // ---- phase 2: ctx[32,512] = P[32,1024] @ vhT[512,1024]^T ----
  const bf16_t* V = vhT + (long)bh * D_ * L_;
  f32x4 acc[2][8] = {};
  for (int k0 = 0; k0 < 1024; k0 += 32) {
    bf16x8 af[2], bfr[8];
    #pragma unroll
    for (int i = 0; i < 2; ++i) {
      const int r = i * 16 + (lane & 15);
      af[i] = *(const bf16x8*)(pb + ((r * 2048 + k0 * 2 + (lane >> 4) * 16) ^ ((r & 7) << 4)));
    }
    #pragma unroll
    for (int j = 0; j < 8; ++j)
      bfr[j] = *(const bf16x8*)(V + (long)(wid * 128 + j * 16 + (lane & 15)) * L_ + k0 + (lane >> 4) * 8);
    #pragma unroll
    for (int i = 0; i < 2; ++i)
      #pragma unroll
      for (int j = 0; j < 8; ++j)
        acc[i][j] = __builtin_amdgcn_mfma_f32_16x16x32_bf16(af[i], bfr[j], acc[i][j], 0, 0, 0);
  }
  bf16_t* C = ctx + (long)(b * L_ + qt * QT_) * HD_ + h * D_;
  #pragma unroll
  for (int i = 0; i < 2; ++i) {
    const int rbase = i * 16 + ((lane >> 4) << 2);
    #pragma unroll
    for (int j = 0; j < 8; ++j) {
      const int c = wid * 128 + j * 16 + (lane & 15);
      #pragma unroll
      for (int r = 0; r < 4; ++r)
        C[(long)(rbase + r) * HD_ + c] = (bf16_t)acc[i][j][r];
    }
  }
}

// ---------------- LayerNorm: one wave per 512-col row, in-place ----------------
__global__ void ln_rows(float* __restrict__ o, const float* __restrict__ g,
                        const float* __restrict__ be) {
  const long row = (long)blockIdx.x * 4 + (threadIdx.x >> 6);
  const int lane = threadIdx.x & 63;
  float* p = o + row * 512;
  float4 a = ((const float4*)p)[lane];
  float4 b = ((const float4*)p)[lane + 64];
  float s  = a.x + a.y + a.z + a.w + b.x + b.y + b.z + b.w;
  float s2 = a.x*a.x + a.y*a.y + a.z*a.z + a.w*a.w
           + b.x*b.x + b.y*b.y + b.z*b.z + b.w*b.w;
  #pragma unroll
  for (int t = 32; t; t >>= 1) { s += __shfl_xor(s, t); s2 += __shfl_xor(s2, t); }
  const float mu  = s * (1.f / 512.f);
  const float var = s2 * (1.f / 512.f) - mu * mu;
  const float inv = rsqrtf(var + 1e-6f);
  float4 g0 = ((const float4*)g)[lane],  g1 = ((const float4*)g)[lane + 64];
  float4 b0 = ((const float4*)be)[lane], b1 = ((const float4*)be)[lane + 64];
  a.x = (a.x - mu) * inv * g0.x + b0.x;  a.y = (a.y - mu) * inv * g0.y + b0.y;
  a.z = (a.z - mu) * inv * g0.z + b0.z;  a.w = (a.w - mu) * inv * g0.w + b0.w;
  b.x = (b.x - mu) * inv * g1.x + b1.x;  b.y = (b.y - mu) * inv * g1.y + b1.y;
  b.z = (b.z - mu) * inv * g1.z + b1.z;  b.w = (b.w - mu) * inv * g1.w + b1.w;
  ((float4*)p)[lane] = a;
  ((float4*)p)[lane + 64] = b;
}

extern "C" void kernel_launch(void* const* d_in, const int* in_sizes, int n_in,
                              void* d_out, int out_size, void* d_ws, size_t ws_size,
                              hipStream_t stream) {
  const float* q   = (const float*)d_in[0];
  const float* k   = (const float*)d_in[1];
  const float* v   = (const float*)d_in[2];
  const float* wq  = (const float*)d_in[3];
  const float* wk  = (const float*)d_in[4];
  const float* wv  = (const float*)d_in[5];
  const float* wfc = (const float*)d_in[6];
  const float* lng = (const float*)d_in[7];
  const float* lnb = (const float*)d_in[8];

  float* out   = (float*)d_out;
  float* attnf = out + (long)BL_ * D_;   // attn output region (B,H,L,L) f32

  char* ws = (char*)d_ws;
  const long MB = 1024 * 1024;
  bf16_t* qbf = (bf16_t*)(ws +   0 * MB);   //  8 MiB
  bf16_t* kbf = (bf16_t*)(ws +   8 * MB);   //  8 MiB
  bf16_t* vbf = (bf16_t*)(ws +  16 * MB);   //  8 MiB
  bf16_t* wqT = (bf16_t*)(ws +  24 * MB);   //  4 MiB  (4096x512)
  bf16_t* wkT = (bf16_t*)(ws +  28 * MB);
  bf16_t* wvT = (bf16_t*)(ws +  32 * MB);
  bf16_t* wfT = (bf16_t*)(ws +  36 * MB);   //  4 MiB  (512x4096)
  bf16_t* qh  = (bf16_t*)(ws +  40 * MB);   // 64 MiB  (8192x4096)
  bf16_t* kh  = (bf16_t*)(ws + 104 * MB);   // 64 MiB
  bf16_t* vh  = (bf16_t*)(ws + 168 * MB);   // 64 MiB
  bf16_t* vhT = (bf16_t*)(ws + 232 * MB);   // 64 MiB  (64 x 512 x 1024)
  bf16_t* ctx = vh;                         // 64 MiB,  reuses vh after transpose

  // 1) converts
  const int n4 = BL_ * D_ / 4;
  f2b<<<dim3(n4 / 256), 256, 0, stream>>>((const float4*)q, (bf16x4*)qbf, n4);
  f2b<<<dim3(n4 / 256), 256, 0, stream>>>((const float4*)k, (bf16x4*)kbf, n4);
  f2b<<<dim3(n4 / 256), 256, 0, stream>>>((const float4*)v, (bf16x4*)vbf, n4);
  tconv<<<dim3(HD_ / 32, D_ / 32), dim3(32, 8), 0, stream>>>(wq,  wqT, D_, HD_);
  tconv<<<dim3(HD_ / 32, D_ / 32), dim3(32, 8), 0, stream>>>(wk,  wkT, D_, HD_);
  tconv<<<dim3(HD_ / 32, D_ / 32), dim3(32, 8), 0, stream>>>(wv,  wvT, D_, HD_);
  tconv<<<dim3(D_ / 32, HD_ / 32), dim3(32, 8), 0, stream>>>(wfc, wfT, HD_, D_);

  // 2) projections (qh pre-scaled by 1/sqrt(D))
  const float qscale = 1.0f / sqrtf((float)D_);
  gemm_bt<0><<<dim3(32, 64, 1), 256, 0, stream>>>(qbf, 0, 0, D_, wqT, 0, 0, D_,
                                                  qh, 0, 0, HD_, D_, qscale, nullptr);
  gemm_bt<0><<<dim3(32, 64, 1), 256, 0, stream>>>(kbf, 0, 0, D_, wkT, 0, 0, D_,
                                                  kh, 0, 0, HD_, D_, 1.0f, nullptr);
  gemm_bt<0><<<dim3(32, 64, 1), 256, 0, stream>>>(vbf, 0, 0, D_, wvT, 0, 0, D_,
                                                  vh, 0, 0, HD_, D_, 1.0f, nullptr);

  // 3) vh -> vhT (per (b,h): (L,D) -> (D,L))
  tbf<<<dim3(D_ / 32, L_ / 32, B_ * H_), dim3(32, 8), 0, stream>>>(vh, vhT);

  // 4) scores = qh @ kh^T per (b,h), f32 into attn output region
  gemm_bt<1><<<dim3(8, 8, B_ * H_), 256, 0, stream>>>(
      qh, (long)L_ * HD_, D_, HD_,
      kh, (long)L_ * HD_, D_, HD_,
      attnf, (long)H_ * L_ * L_, (long)L_ * L_, L_, D_, 1.0f, nullptr);

  // 5) fused softmax (in-place) + PV -> ctx
  smpv<<<dim3(L_ / QT_, B_ * H_), 256, 0, stream>>>(attnf, vhT, ctx);

  // 6) out = ctx @ w_fc + residual(q), f32
  gemm_bt<2><<<dim3(4, 64, 1), 256, 0, stream>>>(
      ctx, 0, 0, HD_, wfT, 0, 0, HD_,
      out, 0, 0, D_, HD_, 1.0f, q);

  // 7) LayerNorm in place
  ln_rows<<<dim3(BL_ / 4), 256, 0, stream>>>(out, lng, lnb);
}

// Round 3
// 700.002 us; speedup vs baseline: 1.1310x; 1.1310x over previous
//
#include <hip/hip_runtime.h>
#include <hip/hip_bf16.h>
#include <math.h>

typedef __bf16 bf16_t;
typedef __bf16 bf16x8 __attribute__((ext_vector_type(8)));
typedef __bf16 bf16x4 __attribute__((ext_vector_type(4)));
typedef float  f32x4  __attribute__((ext_vector_type(4)));

#define B_   8
#define L_   1024
#define D_   512
#define H_   8
#define HD_  4096   // H*D
#define BL_  8192   // B*L

__device__ __forceinline__ void gload_lds16(const bf16_t* g, bf16_t* l) {
  __builtin_amdgcn_global_load_lds(
      (const __attribute__((address_space(1))) unsigned int*)g,
      (__attribute__((address_space(3))) unsigned int*)l,
      16, 0, 0);
}

// ---------------- fp32 -> bf16 convert (vectorized) ----------------
__global__ void f2b(const float4* __restrict__ s, bf16x4* __restrict__ d, int n4) {
  int i = blockIdx.x * blockDim.x + threadIdx.x;
  if (i >= n4) return;
  float4 v = s[i];
  bf16x4 o;
  o[0] = (bf16_t)v.x; o[1] = (bf16_t)v.y; o[2] = (bf16_t)v.z; o[3] = (bf16_t)v.w;
  d[i] = o;
}

// ---------------- transpose + convert fp32(R,C) -> bf16(C,R) ----------------
__global__ void tconv(const float* __restrict__ s, bf16_t* __restrict__ d, int R, int C) {
  __shared__ float t[32][33];
  int c0 = blockIdx.x * 32, r0 = blockIdx.y * 32;
  int tx = threadIdx.x, ty = threadIdx.y;
  #pragma unroll
  for (int i = 0; i < 32; i += 8)
    t[ty + i][tx] = s[(long)(r0 + ty + i) * C + c0 + tx];
  __syncthreads();
  #pragma unroll
  for (int i = 0; i < 32; i += 8)
    d[(long)(c0 + ty + i) * R + r0 + tx] = (bf16_t)t[tx][ty + i];
}

// ------- per-(b,h) transpose bf16: vh_flat(8192,4096) -> vhT[bz](512,1024) -------
__global__ void tbf(const bf16_t* __restrict__ s, bf16_t* __restrict__ d) {
  __shared__ bf16_t t[32][33];
  int bz = blockIdx.z; int b = bz >> 3, h = bz & 7;
  const bf16_t* S = s + (long)b * L_ * HD_ + (long)h * D_;
  bf16_t* Dp = d + (long)bz * D_ * L_;
  int l0 = blockIdx.y * 32, d0 = blockIdx.x * 32;
  int tx = threadIdx.x, ty = threadIdx.y;
  #pragma unroll
  for (int i = 0; i < 32; i += 8)
    t[ty + i][tx] = S[(long)(l0 + ty + i) * HD_ + d0 + tx];
  __syncthreads();
  #pragma unroll
  for (int i = 0; i < 32; i += 8)
    Dp[(long)(d0 + ty + i) * L_ + l0 + tx] = t[tx][ty + i];
}

// ---------------- bf16 GEMM, A(M,K) x Bt(N,K)^T, BMxBN tile, BK=64 ----------------
// BN=128: 4 waves as 2Mx2N, per-wave 64x64.  BN=64: 4 waves as 4Mx1N, per-wave 32x64.
// EPI 0: bf16 store; EPI 1: f32 store; EPI 2: f32 store + residual add
template<int BM, int BN, int EPI>
__launch_bounds__(256, 2)
__global__ void gemm_bt(const bf16_t* __restrict__ A, long sAb, long sAh, int lda,
                        const bf16_t* __restrict__ Bt, long sBb, long sBh, int ldb,
                        void* __restrict__ Cv, long sCb, long sCh, int ldc,
                        int K, float scale, const float* __restrict__ res)
{
  constexpr int WN    = (BN == 128) ? 2 : 1;     // waves along N
  constexpr int SPANM = BM / (4 / WN);           // per-wave rows
  constexpr int MI    = SPANM / 16;
  constexpr int NJ    = 4;
  __shared__ bf16_t sA[BM * 64];
  __shared__ bf16_t sB[BN * 64];
  const int bz = blockIdx.z, b = bz >> 3, h = bz & 7;
  A  += (long)b * sAb + (long)h * sAh;
  Bt += (long)b * sBb + (long)h * sBh;
  const int m0 = blockIdx.y * BM, n0 = blockIdx.x * BN;
  const int tid = threadIdx.x, lane = tid & 63, wid = tid >> 6;
  const int waveM = (WN == 2) ? (wid >> 1) : wid;
  const int waveN = (WN == 2) ? (wid & 1) : 0;
  f32x4 acc[MI][NJ] = {};
  // staging: wave wid, issue j -> global rows j*32 + wid*8 + (lane>>3), cols (lane&7)*8
  // LDS lands linear row-major [rows][64]
  const int srow = wid * 8 + (lane >> 3);
  const int skin = (lane & 7) * 8;
  const bf16_t* Ag = A + (long)(m0 + srow) * lda + skin;
  const bf16_t* Bg = Bt + (long)(n0 + srow) * ldb + skin;
  for (int k0 = 0; k0 < K; k0 += 64) {
    #pragma unroll
    for (int j = 0; j < BM / 32; ++j)
      gload_lds16(Ag + (long)(j * 32) * lda + k0, sA + (j * 4 + wid) * 512);
    #pragma unroll
    for (int j = 0; j < BN / 32; ++j)
      gload_lds16(Bg + (long)(j * 32) * ldb + k0, sB + (j * 4 + wid) * 512);
    __syncthreads();   // drains vmcnt -> LDS writes visible
    #pragma unroll
    for (int kk = 0; kk < 2; ++kk) {
      bf16x8 af[MI], bfr[NJ];
      #pragma unroll
      for (int i = 0; i < MI; ++i)
        af[i]  = *(const bf16x8*)(sA + (waveM * SPANM + i * 16 + (lane & 15)) * 64 + kk * 32 + ((lane >> 4) * 8));
      #pragma unroll
      for (int j = 0; j < NJ; ++j)
        bfr[j] = *(const bf16x8*)(sB + (waveN * 64 + j * 16 + (lane & 15)) * 64 + kk * 32 + ((lane >> 4) * 8));
      #pragma unroll
      for (int i = 0; i < MI; ++i)
        #pragma unroll
        for (int j = 0; j < NJ; ++j)
          acc[i][j] = __builtin_amdgcn_mfma_f32_16x16x32_bf16(af[i], bfr[j], acc[i][j], 0, 0, 0);
    }
    __syncthreads();   // compute done before next-tile overwrite
  }
  const long coff = (long)b * sCb + (long)h * sCh;
  #pragma unroll
  for (int i = 0; i < MI; ++i) {
    const int rbase = m0 + waveM * SPANM + i * 16 + ((lane >> 4) << 2);
    #pragma unroll
    for (int j = 0; j < NJ; ++j) {
      const int c = n0 + waveN * 64 + j * 16 + (lane & 15);
      #pragma unroll
      for (int r = 0; r < 4; ++r) {
        float v = acc[i][j][r] * scale;
        long idx = coff + (long)(rbase + r) * ldc + c;
        if (EPI == 0)      ((bf16_t*)Cv)[idx] = (bf16_t)v;
        else if (EPI == 1) ((float*)Cv)[idx] = v;
        else               ((float*)Cv)[idx] = v + res[(long)(rbase + r) * ldc + c];
      }
    }
  }
}

// ---------------- softmax: one wave per 1024-col row, in-place f32 + bf16 copy ----------------
__global__ void softmax_rows(float* __restrict__ attn, bf16_t* __restrict__ abf) {
  const long row = (long)blockIdx.x * 4 + (threadIdx.x >> 6);
  const int lane = threadIdx.x & 63;
  float* p = attn + row * 1024;
  float4 v[4];
  float m = -1e30f;
  #pragma unroll
  for (int j = 0; j < 4; ++j) {
    v[j] = ((const float4*)p)[j * 64 + lane];
    m = fmaxf(m, fmaxf(fmaxf(v[j].x, v[j].y), fmaxf(v[j].z, v[j].w)));
  }
  #pragma unroll
  for (int o = 32; o; o >>= 1) m = fmaxf(m, __shfl_xor(m, o));
  float s = 0.f;
  #pragma unroll
  for (int j = 0; j < 4; ++j) {
    v[j].x = expf(v[j].x - m); v[j].y = expf(v[j].y - m);
    v[j].z = expf(v[j].z - m); v[j].w = expf(v[j].w - m);
    s += v[j].x + v[j].y + v[j].z + v[j].w;
  }
  #pragma unroll
  for (int o = 32; o; o >>= 1) s += __shfl_xor(s, o);
  const float inv = 1.f / s;
  bf16x4* ab = (bf16x4*)(abf + row * 1024);
  #pragma unroll
  for (int j = 0; j < 4; ++j) {
    v[j].x *= inv; v[j].y *= inv; v[j].z *= inv; v[j].w *= inv;
    ((float4*)p)[j * 64 + lane] = v[j];
    bf16x4 o4;
    o4[0] = (bf16_t)v[j].x; o4[1] = (bf16_t)v[j].y;
    o4[2] = (bf16_t)v[j].z; o4[3] = (bf16_t)v[j].w;
    ab[j * 64 + lane] = o4;
  }
}

// ---------------- LayerNorm: one wave per 512-col row, in-place ----------------
__global__ void ln_rows(float* __restrict__ o, const float* __restrict__ g,
                        const float* __restrict__ be) {
  const long row = (long)blockIdx.x * 4 + (threadIdx.x >> 6);
  const int lane = threadIdx.x & 63;
  float* p = o + row * 512;
  float4 a = ((const float4*)p)[lane];
  float4 b = ((const float4*)p)[lane + 64];
  float s  = a.x + a.y + a.z + a.w + b.x + b.y + b.z + b.w;
  float s2 = a.x*a.x + a.y*a.y + a.z*a.z + a.w*a.w
           + b.x*b.x + b.y*b.y + b.z*b.z + b.w*b.w;
  #pragma unroll
  for (int t = 32; t; t >>= 1) { s += __shfl_xor(s, t); s2 += __shfl_xor(s2, t); }
  const float mu  = s * (1.f / 512.f);
  const float var = s2 * (1.f / 512.f) - mu * mu;
  const float inv = rsqrtf(var + 1e-6f);
  float4 g0 = ((const float4*)g)[lane],  g1 = ((const float4*)g)[lane + 64];
  float4 b0 = ((const float4*)be)[lane], b1 = ((const float4*)be)[lane + 64];
  a.x = (a.x - mu) * inv * g0.x + b0.x;  a.y = (a.y - mu) * inv * g0.y + b0.y;
  a.z = (a.z - mu) * inv * g0.z + b0.z;  a.w = (a.w - mu) * inv * g0.w + b0.w;
  b.x = (b.x - mu) * inv * g1.x + b1.x;  b.y = (b.y - mu) * inv * g1.y + b1.y;
  b.z = (b.z - mu) * inv * g1.z + b1.z;  b.w = (b.w - mu) * inv * g1.w + b1.w;
  ((float4*)p)[lane] = a;
  ((float4*)p)[lane + 64] = b;
}

extern "C" void kernel_launch(void* const* d_in, const int* in_sizes, int n_in,
                              void* d_out, int out_size, void* d_ws, size_t ws_size,
                              hipStream_t stream) {
  const float* q   = (const float*)d_in[0];
  const float* k   = (const float*)d_in[1];
  const float* v   = (const float*)d_in[2];
  const float* wq  = (const float*)d_in[3];
  const float* wk  = (const float*)d_in[4];
  const float* wv  = (const float*)d_in[5];
  const float* wfc = (const float*)d_in[6];
  const float* lng = (const float*)d_in[7];
  const float* lnb = (const float*)d_in[8];

  float* out   = (float*)d_out;
  float* attnf = out + (long)BL_ * D_;   // attn output region (B,H,L,L) f32

  char* ws = (char*)d_ws;
  const long MB = 1024 * 1024;
  bf16_t* qbf = (bf16_t*)(ws +   0 * MB);   //  8 MiB
  bf16_t* kbf = (bf16_t*)(ws +   8 * MB);   //  8 MiB
  bf16_t* vbf = (bf16_t*)(ws +  16 * MB);   //  8 MiB
  bf16_t* wqT = (bf16_t*)(ws +  24 * MB);   //  4 MiB  (4096x512)
  bf16_t* wkT = (bf16_t*)(ws +  28 * MB);
  bf16_t* wvT = (bf16_t*)(ws +  32 * MB);
  bf16_t* wfT = (bf16_t*)(ws +  36 * MB);   //  4 MiB  (512x4096)
  bf16_t* qh  = (bf16_t*)(ws +  40 * MB);   // 64 MiB  (8192x4096)
  bf16_t* kh  = (bf16_t*)(ws + 104 * MB);   // 64 MiB
  bf16_t* vh  = (bf16_t*)(ws + 168 * MB);   // 64 MiB
  bf16_t* vhT = (bf16_t*)(ws + 232 * MB);   // 64 MiB  (64 x 512 x 1024)
  bf16_t* abf = qh;                         // 128 MiB, reuses qh+kh after scores
  bf16_t* ctx = vh;                         // 64 MiB,  reuses vh after transpose

  // 1) converts
  const int n4 = BL_ * D_ / 4;
  f2b<<<dim3(n4 / 256), 256, 0, stream>>>((const float4*)q, (bf16x4*)qbf, n4);
  f2b<<<dim3(n4 / 256), 256, 0, stream>>>((const float4*)k, (bf16x4*)kbf, n4);
  f2b<<<dim3(n4 / 256), 256, 0, stream>>>((const float4*)v, (bf16x4*)vbf, n4);
  tconv<<<dim3(HD_ / 32, D_ / 32), dim3(32, 8), 0, stream>>>(wq,  wqT, D_, HD_);
  tconv<<<dim3(HD_ / 32, D_ / 32), dim3(32, 8), 0, stream>>>(wk,  wkT, D_, HD_);
  tconv<<<dim3(HD_ / 32, D_ / 32), dim3(32, 8), 0, stream>>>(wv,  wvT, D_, HD_);
  tconv<<<dim3(D_ / 32, HD_ / 32), dim3(32, 8), 0, stream>>>(wfc, wfT, HD_, D_);

  // 2) projections (qh pre-scaled by 1/sqrt(D))
  const float qscale = 1.0f / sqrtf((float)D_);
  gemm_bt<128,128,0><<<dim3(32, 64, 1), 256, 0, stream>>>(qbf, 0, 0, D_, wqT, 0, 0, D_,
                                                          qh, 0, 0, HD_, D_, qscale, nullptr);
  gemm_bt<128,128,0><<<dim3(32, 64, 1), 256, 0, stream>>>(kbf, 0, 0, D_, wkT, 0, 0, D_,
                                                          kh, 0, 0, HD_, D_, 1.0f, nullptr);
  gemm_bt<128,128,0><<<dim3(32, 64, 1), 256, 0, stream>>>(vbf, 0, 0, D_, wvT, 0, 0, D_,
                                                          vh, 0, 0, HD_, D_, 1.0f, nullptr);

  // 3) vh -> vhT (per (b,h): (L,D) -> (D,L))
  tbf<<<dim3(D_ / 32, L_ / 32, B_ * H_), dim3(32, 8), 0, stream>>>(vh, vhT);

  // 4) scores = qh @ kh^T per (b,h), f32 into attn output region
  gemm_bt<128,128,1><<<dim3(8, 8, B_ * H_), 256, 0, stream>>>(
      qh, (long)L_ * HD_, D_, HD_,
      kh, (long)L_ * HD_, D_, HD_,
      attnf, (long)H_ * L_ * L_, (long)L_ * L_, L_, D_, 1.0f, nullptr);

  // 5) softmax in place + bf16 mirror (overwrites qh/kh region)
  softmax_rows<<<dim3(B_ * H_ * L_ / 4), 256, 0, stream>>>(attnf, abf);

  // 6) ctx = attn @ vh per (b,h), bf16 into flat (B*L, H*D)
  gemm_bt<128,128,0><<<dim3(4, 8, B_ * H_), 256, 0, stream>>>(
      abf, (long)H_ * L_ * L_, (long)L_ * L_, L_,
      vhT, (long)H_ * D_ * L_, (long)D_ * L_, L_,
      ctx, (long)L_ * HD_, D_, HD_, L_, 1.0f, nullptr);

  // 7) out = ctx @ w_fc + residual(q), f32 — 128x64 tile: 512 blocks (2+/CU)
  gemm_bt<128,64,2><<<dim3(8, 64, 1), 256, 0, stream>>>(
      ctx, 0, 0, HD_, wfT, 0, 0, HD_,
      out, 0, 0, D_, HD_, 1.0f, q);

  // 8) LayerNorm in place
  ln_rows<<<dim3(BL_ / 4), 256, 0, stream>>>(out, lng, lnb);
}

// Round 4
// 646.082 us; speedup vs baseline: 1.2253x; 1.0835x over previous
//
#include <hip/hip_runtime.h>
#include <hip/hip_bf16.h>
#include <math.h>

typedef __bf16 bf16_t;
typedef __bf16 bf16x8 __attribute__((ext_vector_type(8)));
typedef __bf16 bf16x4 __attribute__((ext_vector_type(4)));
typedef float  f32x4  __attribute__((ext_vector_type(4)));

#define B_   8
#define L_   1024
#define D_   512
#define H_   8
#define HD_  4096   // H*D
#define BL_  8192   // B*L

__device__ __forceinline__ void gload_lds16(const bf16_t* g, bf16_t* l) {
  __builtin_amdgcn_global_load_lds(
      (const __attribute__((address_space(1))) unsigned int*)g,
      (__attribute__((address_space(3))) unsigned int*)l,
      16, 0, 0);
}

// ---------------- fp32 -> bf16 convert (vectorized) ----------------
__global__ void f2b(const float4* __restrict__ s, bf16x4* __restrict__ d, int n4) {
  int i = blockIdx.x * blockDim.x + threadIdx.x;
  if (i >= n4) return;
  float4 v = s[i];
  bf16x4 o;
  o[0] = (bf16_t)v.x; o[1] = (bf16_t)v.y; o[2] = (bf16_t)v.z; o[3] = (bf16_t)v.w;
  d[i] = o;
}

// ---------------- transpose + convert fp32(R,C) -> bf16(C,R) ----------------
__global__ void tconv(const float* __restrict__ s, bf16_t* __restrict__ d, int R, int C) {
  __shared__ float t[32][33];
  int c0 = blockIdx.x * 32, r0 = blockIdx.y * 32;
  int tx = threadIdx.x, ty = threadIdx.y;
  #pragma unroll
  for (int i = 0; i < 32; i += 8)
    t[ty + i][tx] = s[(long)(r0 + ty + i) * C + c0 + tx];
  __syncthreads();
  #pragma unroll
  for (int i = 0; i < 32; i += 8)
    d[(long)(c0 + ty + i) * R + r0 + tx] = (bf16_t)t[tx][ty + i];
}

// ------- per-(b,h) transpose bf16: vh_flat(8192,4096) -> vhT[bz](512,1024) -------
__global__ void tbf(const bf16_t* __restrict__ s, bf16_t* __restrict__ d) {
  __shared__ bf16_t t[32][33];
  int bz = blockIdx.z; int b = bz >> 3, h = bz & 7;
  const bf16_t* S = s + (long)b * L_ * HD_ + (long)h * D_;
  bf16_t* Dp = d + (long)bz * D_ * L_;
  int l0 = blockIdx.y * 32, d0 = blockIdx.x * 32;
  int tx = threadIdx.x, ty = threadIdx.y;
  #pragma unroll
  for (int i = 0; i < 32; i += 8)
    t[ty + i][tx] = S[(long)(l0 + ty + i) * HD_ + d0 + tx];
  __syncthreads();
  #pragma unroll
  for (int i = 0; i < 32; i += 8)
    Dp[(long)(d0 + ty + i) * L_ + l0 + tx] = t[tx][ty + i];
}

// ================= 256x256 8-phase GEMM, A(M,K) x Bt(N,K)^T =================
// 8 waves (2M x 4N), BK=64 split as two kk-halves, 2 K-tiles per iteration,
// double-buffered 128KB LDS, counted vmcnt(4) at phases 4/8, setprio on MFMA.
// LDS layout (bf16 elems): buf*32768 + op*16384 + kk*8192 + row*32 + slot*8,
// slot swizzled by (row>>1)&3 on BOTH staging-source and ds_read (involution).
// EPI 0: bf16 store; EPI 1: f32 store.

#define VM4 asm volatile("s_waitcnt vmcnt(4)" ::: "memory")
#define VM0 asm volatile("s_waitcnt vmcnt(0)" ::: "memory")

#define STG(OP, BUF, KK, TILE) do { \
  const bf16_t* gsrc_ = (OP) ? Bg : Ag; \
  const long gld_ = (OP) ? ldb : lda; \
  bf16_t* lb_ = lds + (BUF)*32768 + (OP)*16384 + (KK)*8192 + wid*512; \
  gload_lds16(gsrc_ + (long)(TILE)*64 + (KK)*32, lb_); \
  gload_lds16(gsrc_ + (long)128*gld_ + (long)(TILE)*64 + (KK)*32, lb_ + 4096); \
} while (0)

#define LDA(I, BUF, KK) (*(const bf16x8*)(lds + (BUF)*32768 + (KK)*8192 + offA[I]))
#define LDB(J, BUF, KK) (*(const bf16x8*)(lds + (BUF)*32768 + 16384 + (KK)*8192 + offB[J]))

#define MM(q, ii, jj) acc[(q)*4+(ii)][(jj)] = \
  __builtin_amdgcn_mfma_f32_16x16x32_bf16(a##ii, b##jj, acc[(q)*4+(ii)][(jj)], 0, 0, 0)

#define PHASE(Q, KK, BUF, STAGE, VM) do { \
  bf16x8 a0, a1, a2, a3; \
  if ((Q) == 0) { b0 = LDB(0,BUF,KK); b1 = LDB(1,BUF,KK); b2 = LDB(2,BUF,KK); b3 = LDB(3,BUF,KK); } \
  a0 = LDA((Q)*4+0,BUF,KK); a1 = LDA((Q)*4+1,BUF,KK); \
  a2 = LDA((Q)*4+2,BUF,KK); a3 = LDA((Q)*4+3,BUF,KK); \
  STAGE; \
  __builtin_amdgcn_s_barrier(); \
  asm volatile("s_waitcnt lgkmcnt(0)" ::: "memory"); \
  __builtin_amdgcn_sched_barrier(0); \
  __builtin_amdgcn_s_setprio(1); \
  MM(Q,0,0); MM(Q,1,0); MM(Q,2,0); MM(Q,3,0); \
  MM(Q,0,1); MM(Q,1,1); MM(Q,2,1); MM(Q,3,1); \
  MM(Q,0,2); MM(Q,1,2); MM(Q,2,2); MM(Q,3,2); \
  MM(Q,0,3); MM(Q,1,3); MM(Q,2,3); MM(Q,3,3); \
  __builtin_amdgcn_s_setprio(0); \
  VM; \
  __builtin_amdgcn_s_barrier(); \
} while (0)

template<int EPI>
__launch_bounds__(512, 2)
__global__ void gemm256(const bf16_t* __restrict__ A, long sAb, long sAh, int lda,
                        const bf16_t* __restrict__ Bt, long sBb, long sBh, int ldb,
                        void* __restrict__ Cv, long sCb, long sCh, int ldc,
                        int K, float scale)
{
  __shared__ __align__(16) bf16_t lds[65536];   // 128 KiB
  const int bz = blockIdx.z, b = bz >> 3, h = bz & 7;
  A  += (long)b * sAb + (long)h * sAh;
  Bt += (long)b * sBb + (long)h * sBh;
  const int m0 = blockIdx.y * 256, n0 = blockIdx.x * 256;
  const int tid = threadIdx.x, lane = tid & 63, wid = tid >> 6;
  const int wm = wid >> 2, wn = wid & 3;

  // staging source (pre-swizzled slot so linear LDS dest ends up swizzled)
  const int srow  = tid >> 2;                       // 0..127 within an 8KB issue
  const int sslot = (lane & 3) ^ ((tid >> 3) & 3);  // = (lds_row>>1)&3 involution
  const bf16_t* Ag = A + (long)(m0 + srow) * lda + sslot * 8;
  const bf16_t* Bg = Bt + (long)(n0 + srow) * ldb + sslot * 8;

  // ds_read fragment offsets (swizzled with the same involution)
  int offA[8], offB[4];
  #pragma unroll
  for (int i = 0; i < 8; ++i) {
    const int r = wm * 128 + i * 16 + (lane & 15);
    offA[i] = r * 32 + (((lane >> 4) ^ ((r >> 1) & 3)) * 8);
  }
  #pragma unroll
  for (int j = 0; j < 4; ++j) {
    const int r = wn * 64 + j * 16 + (lane & 15);
    offB[j] = r * 32 + (((lane >> 4) ^ ((r >> 1) & 3)) * 8);
  }

  f32x4 acc[8][4] = {};
  const int ITER = K >> 7;    // two BK=64 tiles per iteration

  // prologue: buf0 <- tile0 (all 4 halves), buf1 <- tile1 kk0 halves
  STG(0,0,0,0); STG(0,0,1,0); STG(1,0,0,0); STG(1,0,1,0);
  STG(0,1,0,1); STG(1,1,0,1);
  VM4;                                  // buf0 fully landed (leaves 4 in flight)
  __builtin_amdgcn_s_barrier();

  for (int i = 0; i < ITER; ++i) {
    const int t = 2 * i;
    const bool stg = (i + 1 < ITER);
    bf16x8 b0, b1, b2, b3;
    PHASE(0,0,0, STG(0,1,1,t+1);                , (void)0);
    PHASE(1,0,0, STG(1,1,1,t+1);                , (void)0);
    PHASE(0,1,0, { if (stg) STG(0,0,0,t+2); }   , (void)0);
    PHASE(1,1,0, { if (stg) STG(1,0,0,t+2); }   , { if (stg) { VM4; } else { VM0; } });
    PHASE(0,0,1, { if (stg) STG(0,0,1,t+2); }   , (void)0);
    PHASE(1,0,1, { if (stg) STG(1,0,1,t+2); }   , (void)0);
    PHASE(0,1,1, { if (stg) STG(0,1,0,t+3); }   , (void)0);
    PHASE(1,1,1, { if (stg) STG(1,1,0,t+3); }   , { if (stg) { VM4; } });
  }

  const long coff = (long)b * sCb + (long)h * sCh;
  #pragma unroll
  for (int i = 0; i < 8; ++i) {
    const int rbase = m0 + wm * 128 + i * 16 + ((lane >> 4) << 2);
    #pragma unroll
    for (int j = 0; j < 4; ++j) {
      const int c = n0 + wn * 64 + j * 16 + (lane & 15);
      #pragma unroll
      for (int r = 0; r < 4; ++r) {
        float vv = acc[i][j][r] * scale;
        long idx = coff + (long)(rbase + r) * ldc + c;
        if (EPI == 0) ((bf16_t*)Cv)[idx] = (bf16_t)vv;
        else          ((float*)Cv)[idx] = vv;
      }
    }
  }
}

// ---------------- bf16 GEMM, A(M,K) x Bt(N,K)^T, BMxBN tile, BK=64 ----------------
// (kept for the out-projection: 128x64 tile -> 512 blocks)
template<int BM, int BN, int EPI>
__launch_bounds__(256, 2)
__global__ void gemm_bt(const bf16_t* __restrict__ A, long sAb, long sAh, int lda,
                        const bf16_t* __restrict__ Bt, long sBb, long sBh, int ldb,
                        void* __restrict__ Cv, long sCb, long sCh, int ldc,
                        int K, float scale, const float* __restrict__ res)
{
  constexpr int WN    = (BN == 128) ? 2 : 1;
  constexpr int SPANM = BM / (4 / WN);
  constexpr int MI    = SPANM / 16;
  constexpr int NJ    = 4;
  __shared__ bf16_t sA[BM * 64];
  __shared__ bf16_t sB[BN * 64];
  const int bz = blockIdx.z, b = bz >> 3, h = bz & 7;
  A  += (long)b * sAb + (long)h * sAh;
  Bt += (long)b * sBb + (long)h * sBh;
  const int m0 = blockIdx.y * BM, n0 = blockIdx.x * BN;
  const int tid = threadIdx.x, lane = tid & 63, wid = tid >> 6;
  const int waveM = (WN == 2) ? (wid >> 1) : wid;
  const int waveN = (WN == 2) ? (wid & 1) : 0;
  f32x4 acc[MI][NJ] = {};
  const int srow = wid * 8 + (lane >> 3);
  const int skin = (lane & 7) * 8;
  const bf16_t* Ag = A + (long)(m0 + srow) * lda + skin;
  const bf16_t* Bg = Bt + (long)(n0 + srow) * ldb + skin;
  for (int k0 = 0; k0 < K; k0 += 64) {
    #pragma unroll
    for (int j = 0; j < BM / 32; ++j)
      gload_lds16(Ag + (long)(j * 32) * lda + k0, sA + (j * 4 + wid) * 512);
    #pragma unroll
    for (int j = 0; j < BN / 32; ++j)
      gload_lds16(Bg + (long)(j * 32) * ldb + k0, sB + (j * 4 + wid) * 512);
    __syncthreads();
    #pragma unroll
    for (int kk = 0; kk < 2; ++kk) {
      bf16x8 af[MI], bfr[NJ];
      #pragma unroll
      for (int i = 0; i < MI; ++i)
        af[i]  = *(const bf16x8*)(sA + (waveM * SPANM + i * 16 + (lane & 15)) * 64 + kk * 32 + ((lane >> 4) * 8));
      #pragma unroll
      for (int j = 0; j < NJ; ++j)
        bfr[j] = *(const bf16x8*)(sB + (waveN * 64 + j * 16 + (lane & 15)) * 64 + kk * 32 + ((lane >> 4) * 8));
      #pragma unroll
      for (int i = 0; i < MI; ++i)
        #pragma unroll
        for (int j = 0; j < NJ; ++j)
          acc[i][j] = __builtin_amdgcn_mfma_f32_16x16x32_bf16(af[i], bfr[j], acc[i][j], 0, 0, 0);
    }
    __syncthreads();
  }
  const long coff = (long)b * sCb + (long)h * sCh;
  #pragma unroll
  for (int i = 0; i < MI; ++i) {
    const int rbase = m0 + waveM * SPANM + i * 16 + ((lane >> 4) << 2);
    #pragma unroll
    for (int j = 0; j < NJ; ++j) {
      const int c = n0 + waveN * 64 + j * 16 + (lane & 15);
      #pragma unroll
      for (int r = 0; r < 4; ++r) {
        float v = acc[i][j][r] * scale;
        long idx = coff + (long)(rbase + r) * ldc + c;
        if (EPI == 0)      ((bf16_t*)Cv)[idx] = (bf16_t)v;
        else if (EPI == 1) ((float*)Cv)[idx] = v;
        else               ((float*)Cv)[idx] = v + res[(long)(rbase + r) * ldc + c];
      }
    }
  }
}

// ---------------- softmax: one wave per 1024-col row, in-place f32 + bf16 copy ----------------
__global__ void softmax_rows(float* __restrict__ attn, bf16_t* __restrict__ abf) {
  const long row = (long)blockIdx.x * 4 + (threadIdx.x >> 6);
  const int lane = threadIdx.x & 63;
  float* p = attn + row * 1024;
  float4 v[4];
  float m = -1e30f;
  #pragma unroll
  for (int j = 0; j < 4; ++j) {
    v[j] = ((const float4*)p)[j * 64 + lane];
    m = fmaxf(m, fmaxf(fmaxf(v[j].x, v[j].y), fmaxf(v[j].z, v[j].w)));
  }
  #pragma unroll
  for (int o = 32; o; o >>= 1) m = fmaxf(m, __shfl_xor(m, o));
  float s = 0.f;
  #pragma unroll
  for (int j = 0; j < 4; ++j) {
    v[j].x = expf(v[j].x - m); v[j].y = expf(v[j].y - m);
    v[j].z = expf(v[j].z - m); v[j].w = expf(v[j].w - m);
    s += v[j].x + v[j].y + v[j].z + v[j].w;
  }
  #pragma unroll
  for (int o = 32; o; o >>= 1) s += __shfl_xor(s, o);
  const float inv = 1.f / s;
  bf16x4* ab = (bf16x4*)(abf + row * 1024);
  #pragma unroll
  for (int j = 0; j < 4; ++j) {
    v[j].x *= inv; v[j].y *= inv; v[j].z *= inv; v[j].w *= inv;
    ((float4*)p)[j * 64 + lane] = v[j];
    bf16x4 o4;
    o4[0] = (bf16_t)v[j].x; o4[1] = (bf16_t)v[j].y;
    o4[2] = (bf16_t)v[j].z; o4[3] = (bf16_t)v[j].w;
    ab[j * 64 + lane] = o4;
  }
}

// ---------------- LayerNorm: one wave per 512-col row, in-place ----------------
__global__ void ln_rows(float* __restrict__ o, const float* __restrict__ g,
                        const float* __restrict__ be) {
  const long row = (long)blockIdx.x * 4 + (threadIdx.x >> 6);
  const int lane = threadIdx.x & 63;
  float* p = o + row * 512;
  float4 a = ((const float4*)p)[lane];
  float4 b = ((const float4*)p)[lane + 64];
  float s  = a.x + a.y + a.z + a.w + b.x + b.y + b.z + b.w;
  float s2 = a.x*a.x + a.y*a.y + a.z*a.z + a.w*a.w
           + b.x*b.x + b.y*b.y + b.z*b.z + b.w*b.w;
  #pragma unroll
  for (int t = 32; t; t >>= 1) { s += __shfl_xor(s, t); s2 += __shfl_xor(s2, t); }
  const float mu  = s * (1.f / 512.f);
  const float var = s2 * (1.f / 512.f) - mu * mu;
  const float inv = rsqrtf(var + 1e-6f);
  float4 g0 = ((const float4*)g)[lane],  g1 = ((const float4*)g)[lane + 64];
  float4 b0 = ((const float4*)be)[lane], b1 = ((const float4*)be)[lane + 64];
  a.x = (a.x - mu) * inv * g0.x + b0.x;  a.y = (a.y - mu) * inv * g0.y + b0.y;
  a.z = (a.z - mu) * inv * g0.z + b0.z;  a.w = (a.w - mu) * inv * g0.w + b0.w;
  b.x = (b.x - mu) * inv * g1.x + b1.x;  b.y = (b.y - mu) * inv * g1.y + b1.y;
  b.z = (b.z - mu) * inv * g1.z + b1.z;  b.w = (b.w - mu) * inv * g1.w + b1.w;
  ((float4*)p)[lane] = a;
  ((float4*)p)[lane + 64] = b;
}

extern "C" void kernel_launch(void* const* d_in, const int* in_sizes, int n_in,
                              void* d_out, int out_size, void* d_ws, size_t ws_size,
                              hipStream_t stream) {
  const float* q   = (const float*)d_in[0];
  const float* k   = (const float*)d_in[1];
  const float* v   = (const float*)d_in[2];
  const float* wq  = (const float*)d_in[3];
  const float* wk  = (const float*)d_in[4];
  const float* wv  = (const float*)d_in[5];
  const float* wfc = (const float*)d_in[6];
  const float* lng = (const float*)d_in[7];
  const float* lnb = (const float*)d_in[8];

  float* out   = (float*)d_out;
  float* attnf = out + (long)BL_ * D_;   // attn output region (B,H,L,L) f32

  char* ws = (char*)d_ws;
  const long MB = 1024 * 1024;
  bf16_t* qbf = (bf16_t*)(ws +   0 * MB);   //  8 MiB
  bf16_t* kbf = (bf16_t*)(ws +   8 * MB);   //  8 MiB
  bf16_t* vbf = (bf16_t*)(ws +  16 * MB);   //  8 MiB
  bf16_t* wqT = (bf16_t*)(ws +  24 * MB);   //  4 MiB  (4096x512)
  bf16_t* wkT = (bf16_t*)(ws +  28 * MB);
  bf16_t* wvT = (bf16_t*)(ws +  32 * MB);
  bf16_t* wfT = (bf16_t*)(ws +  36 * MB);   //  4 MiB  (512x4096)
  bf16_t* qh  = (bf16_t*)(ws +  40 * MB);   // 64 MiB  (8192x4096)
  bf16_t* kh  = (bf16_t*)(ws + 104 * MB);   // 64 MiB
  bf16_t* vh  = (bf16_t*)(ws + 168 * MB);   // 64 MiB
  bf16_t* vhT = (bf16_t*)(ws + 232 * MB);   // 64 MiB  (64 x 512 x 1024)
  bf16_t* abf = qh;                         // 128 MiB, reuses qh+kh after scores
  bf16_t* ctx = vh;                         // 64 MiB,  reuses vh after transpose

  // 1) converts
  const int n4 = BL_ * D_ / 4;
  f2b<<<dim3(n4 / 256), 256, 0, stream>>>((const float4*)q, (bf16x4*)qbf, n4);
  f2b<<<dim3(n4 / 256), 256, 0, stream>>>((const float4*)k, (bf16x4*)kbf, n4);
  f2b<<<dim3(n4 / 256), 256, 0, stream>>>((const float4*)v, (bf16x4*)vbf, n4);
  tconv<<<dim3(HD_ / 32, D_ / 32), dim3(32, 8), 0, stream>>>(wq,  wqT, D_, HD_);
  tconv<<<dim3(HD_ / 32, D_ / 32), dim3(32, 8), 0, stream>>>(wk,  wkT, D_, HD_);
  tconv<<<dim3(HD_ / 32, D_ / 32), dim3(32, 8), 0, stream>>>(wv,  wvT, D_, HD_);
  tconv<<<dim3(D_ / 32, HD_ / 32), dim3(32, 8), 0, stream>>>(wfc, wfT, HD_, D_);

  // 2) projections (qh pre-scaled by 1/sqrt(D)) — 256x256 8-phase
  const float qscale = 1.0f / sqrtf((float)D_);
  gemm256<0><<<dim3(16, 32, 1), 512, 0, stream>>>(qbf, 0, 0, D_, wqT, 0, 0, D_,
                                                  qh, 0, 0, HD_, D_, qscale);
  gemm256<0><<<dim3(16, 32, 1), 512, 0, stream>>>(kbf, 0, 0, D_, wkT, 0, 0, D_,
                                                  kh, 0, 0, HD_, D_, 1.0f);
  gemm256<0><<<dim3(16, 32, 1), 512, 0, stream>>>(vbf, 0, 0, D_, wvT, 0, 0, D_,
                                                  vh, 0, 0, HD_, D_, 1.0f);

  // 3) vh -> vhT (per (b,h): (L,D) -> (D,L))
  tbf<<<dim3(D_ / 32, L_ / 32, B_ * H_), dim3(32, 8), 0, stream>>>(vh, vhT);

  // 4) scores = qh @ kh^T per (b,h), f32 into attn output region
  gemm256<1><<<dim3(4, 4, B_ * H_), 512, 0, stream>>>(
      qh, (long)L_ * HD_, D_, HD_,
      kh, (long)L_ * HD_, D_, HD_,
      attnf, (long)H_ * L_ * L_, (long)L_ * L_, L_, D_, 1.0f);

  // 5) softmax in place + bf16 mirror (overwrites qh/kh region)
  softmax_rows<<<dim3(B_ * H_ * L_ / 4), 256, 0, stream>>>(attnf, abf);

  // 6) ctx = attn @ vh per (b,h), bf16 into flat (B*L, H*D)
  gemm256<0><<<dim3(2, 4, B_ * H_), 512, 0, stream>>>(
      abf, (long)H_ * L_ * L_, (long)L_ * L_, L_,
      vhT, (long)H_ * D_ * L_, (long)D_ * L_, L_,
      ctx, (long)L_ * HD_, D_, HD_, L_, 1.0f);

  // 7) out = ctx @ w_fc + residual(q), f32 — 128x64 tile: 512 blocks
  gemm_bt<128,64,2><<<dim3(8, 64, 1), 256, 0, stream>>>(
      ctx, 0, 0, HD_, wfT, 0, 0, HD_,
      out, 0, 0, D_, HD_, 1.0f, q);

  // 8) LayerNorm in place
  ln_rows<<<dim3(BL_ / 4), 256, 0, stream>>>(out, lng, lnb);
}